// Round 1
// baseline (529.464 us; speedup 1.0000x reference)
//
#include <hip/hip_runtime.h>
#include <hip/hip_bf16.h>

#define LSEQ   2048
#define DK     64
#define NH     16
#define BS     2
#define DMODEL 1024
#define BH     (BS*NH)    // 32
#define MTOT   (BS*LSEQ)  // 4096

typedef __attribute__((ext_vector_type(8))) short bf16x8;
typedef __attribute__((ext_vector_type(4))) float f32x4;

#define MFMA16(a,b,c) __builtin_amdgcn_mfma_f32_16x16x32_bf16((a),(b),(c),0,0,0)
#define GLD_LDS(g,l) __builtin_amdgcn_global_load_lds((const __attribute__((address_space(1))) void*)(g), (__attribute__((address_space(3))) void*)(l), 16, 0, 0)

__device__ __forceinline__ short f2bs(float f) {
  union { __hip_bfloat16 h; short s; } u; u.h = __float2bfloat16(f); return u.s;
}
__device__ __forceinline__ float b2f(unsigned short s) {
  union { unsigned u; float f; } v; v.u = ((unsigned)s) << 16; return v.f;
}
__device__ __forceinline__ unsigned pk2(float lo, float hi) {
  return (unsigned)(unsigned short)f2bs(lo) | (((unsigned)(unsigned short)f2bs(hi)) << 16);
}

// ---------------- f32 -> bf16 flat convert (vectorized) ----------------
__global__ __launch_bounds__(256) void cvt_bf16_k(const float* __restrict__ in,
                                                  short* __restrict__ out, int n8) {
  for (int i = blockIdx.x * blockDim.x + threadIdx.x; i < n8; i += gridDim.x * blockDim.x) {
    const float4* p = (const float4*)in + (size_t)i * 2;
    float4 a = p[0], b = p[1];
    uint4 o;
    o.x = pk2(a.x, a.y); o.y = pk2(a.z, a.w);
    o.z = pk2(b.x, b.y); o.w = pk2(b.z, b.w);
    ((uint4*)out)[i] = o;
  }
}

// ---------------- f32 [K][N] -> bf16 transposed [N][K] ----------------
__global__ __launch_bounds__(256) void cvt_tr_k(const float* __restrict__ W,
                                                short* __restrict__ Wt,
                                                int Krows, int Ncols) {
  __shared__ float tile[32][33];
  int n0 = blockIdx.x * 32, k0 = blockIdx.y * 32;
  int t = threadIdx.x;
#pragma unroll
  for (int i = 0; i < 4; ++i) {
    int idx = t + i * 256; int r = idx >> 5, c = idx & 31;
    tile[r][c] = W[(size_t)(k0 + r) * Ncols + n0 + c];
  }
  __syncthreads();
#pragma unroll
  for (int i = 0; i < 4; ++i) {
    int idx = t + i * 256; int r = idx >> 5, c = idx & 31;
    Wt[(size_t)(n0 + r) * Krows + k0 + c] = f2bs(tile[c][r]);
  }
}

// ---------------- 128x128-tile bf16 GEMM, K=1024 ----------------
// C[m][n] = sum_k A[m][k] * Bt[n][k] + bias[n]
// mode 0: QKV scatter epilogue (bf16 to Qb/Kb head-major, VTb transposed)
// mode 1: f32 row-major to outF (ld 1024)
__global__ __launch_bounds__(256) void gemm128_k(
    const short* __restrict__ A, const short* __restrict__ Bt,
    const float* __restrict__ bias, int mode,
    float* __restrict__ outF,
    short* __restrict__ Qb, short* __restrict__ Kb, short* __restrict__ VTb) {
  __shared__ short As[128 * 64];
  __shared__ short Bs[128 * 64];
  int tid = threadIdx.x, w = tid >> 6, ln = tid & 63, lg = ln >> 4, lr = ln & 15;
  int m0 = blockIdx.x * 128, n0 = blockIdx.y * 128;
  int wr = w >> 1, wc = w & 1;
  f32x4 acc[4][4] = {};

  for (int k0 = 0; k0 < 1024; k0 += 64) {
    __syncthreads();
#pragma unroll
    for (int i = 0; i < 4; ++i) {
      int cb = w * 64 + i * 256;
      int c = cb + ln;
      GLD_LDS(A  + (size_t)(m0 + (c >> 3)) * 1024 + k0 + (c & 7) * 8, &As[cb * 8]);
      GLD_LDS(Bt + (size_t)(n0 + (c >> 3)) * 1024 + k0 + (c & 7) * 8, &Bs[cb * 8]);
    }
    __syncthreads();
#pragma unroll
    for (int kh = 0; kh < 2; ++kh) {
      bf16x8 af[4], bfr[4];
#pragma unroll
      for (int mi = 0; mi < 4; ++mi)
        af[mi] = *(const bf16x8*)&As[(wr * 64 + mi * 16 + lr) * 64 + kh * 32 + lg * 8];
#pragma unroll
      for (int ni = 0; ni < 4; ++ni)
        bfr[ni] = *(const bf16x8*)&Bs[(wc * 64 + ni * 16 + lr) * 64 + kh * 32 + lg * 8];
#pragma unroll
      for (int mi = 0; mi < 4; ++mi)
#pragma unroll
        for (int ni = 0; ni < 4; ++ni)
          acc[mi][ni] = MFMA16(af[mi], bfr[ni], acc[mi][ni]);
    }
  }

#pragma unroll
  for (int ni = 0; ni < 4; ++ni) {
    int n = n0 + wc * 64 + ni * 16 + lr;
    float bv = bias[n];
#pragma unroll
    for (int mi = 0; mi < 4; ++mi) {
#pragma unroll
      for (int r = 0; r < 4; ++r) {
        int m = m0 + wr * 64 + mi * 16 + 4 * lg + r;
        float v = acc[mi][ni][r] + bv;
        if (mode == 1) {
          outF[(size_t)m * 1024 + n] = v;
        } else {
          int part = n >> 10, cc = n & 1023, h = cc >> 6, dd = cc & 63;
          int b = m >> 11, tok = m & 2047, bh = b * NH + h;
          short sv = f2bs(v);
          if (part == 0)      Qb[((size_t)bh * LSEQ + tok) * DK + dd] = sv;
          else if (part == 1) Kb[((size_t)bh * LSEQ + tok) * DK + dd] = sv;
          else                VTb[((size_t)bh * DK + dd) * LSEQ + tok] = sv;
        }
      }
    }
  }
}

// ---------------- per-row squared norms ----------------
__global__ __launch_bounds__(256) void norms_k(
    const short* __restrict__ Qm, const short* __restrict__ Qs,
    const short* __restrict__ Km, const short* __restrict__ Ks,
    float* __restrict__ sqq, float* __restrict__ sqk) {
  int id = blockIdx.x * 256 + threadIdx.x;  // 0..131071
  int row = id & 65535;
  const short* p1 = (id < 65536) ? Qm : Km;
  const short* p2 = (id < 65536) ? Qs : Ks;
  float* outp = (id < 65536) ? sqq : sqk;
  const uint4* a = (const uint4*)(p1 + (size_t)row * DK);
  const uint4* b = (const uint4*)(p2 + (size_t)row * DK);
  float s = 0.f;
#pragma unroll
  for (int i = 0; i < 8; ++i) {
    uint4 x = a[i], y = b[i];
    unsigned vx[4] = {x.x, x.y, x.z, x.w};
    unsigned vy[4] = {y.x, y.y, y.z, y.w};
#pragma unroll
    for (int j = 0; j < 4; ++j) {
      float l1 = b2f((unsigned short)(vx[j] & 0xffff)), h1 = b2f((unsigned short)(vx[j] >> 16));
      float l2 = b2f((unsigned short)(vy[j] & 0xffff)), h2 = b2f((unsigned short)(vy[j] >> 16));
      s += l1 * l1 + h1 * h1 + l2 * l2 + h2 * h2;
    }
  }
  outp[row] = s;
}

// ---------------- fused Wasserstein attention ----------------
// grid (L/64, BH); 256 threads = 4 waves, wave w owns q-rows [q0+16w, q0+16w+16)
__global__ __launch_bounds__(256) void attn_k(
    const short* __restrict__ Qm, const short* __restrict__ Km, const short* __restrict__ VmT,
    const short* __restrict__ Qs, const short* __restrict__ Ks, const short* __restrict__ VsT,
    const float* __restrict__ sqq, const float* __restrict__ sqk,
    short* __restrict__ Om, short* __restrict__ Os) {
  int bh = blockIdx.y;
  int q0 = blockIdx.x * 64;
  int tid = threadIdx.x, w = tid >> 6, ln = tid & 63, lg = ln >> 4, lr = ln & 15;

  __shared__ short Km_t[64][72];
  __shared__ short Ks_t[64][72];
  __shared__ short Vt_t[128][72];
  __shared__ short P_t[4][16][72];

  const size_t bhQ = (size_t)bh * LSEQ * DK;

  // Q fragments for this wave's 16 rows (A-frag: row=lr, k = lg*8 + kh*32)
  bf16x8 qm[2], qs[2];
  {
    const short* qpm = Qm + bhQ + (size_t)(q0 + w * 16 + lr) * DK;
    const short* qps = Qs + bhQ + (size_t)(q0 + w * 16 + lr) * DK;
    qm[0] = *(const bf16x8*)(qpm + lg * 8);
    qm[1] = *(const bf16x8*)(qpm + 32 + lg * 8);
    qs[0] = *(const bf16x8*)(qps + lg * 8);
    qs[1] = *(const bf16x8*)(qps + 32 + lg * 8);
  }
  float sq_row[4];
#pragma unroll
  for (int r = 0; r < 4; ++r)
    sq_row[r] = sqq[(size_t)bh * LSEQ + q0 + w * 16 + 4 * lg + r];

  f32x4 acc[8] = {};
  float prs[4] = {0.f, 0.f, 0.f, 0.f};

  for (int kt = 0; kt < LSEQ / 64; ++kt) {
    int k0 = kt * 64;
    __syncthreads();
    // stage K tiles [64][64]
#pragma unroll
    for (int i = 0; i < 2; ++i) {
      int c = tid + i * 256; int row = c >> 3, sl = c & 7;
      *(int4*)&Km_t[row][sl * 8] = *(const int4*)(Km + bhQ + (size_t)(k0 + row) * DK + sl * 8);
      *(int4*)&Ks_t[row][sl * 8] = *(const int4*)(Ks + bhQ + (size_t)(k0 + row) * DK + sl * 8);
    }
    // stage V^T tile [128][64]: rows 0..63 = VmT dims, 64..127 = VsT dims
#pragma unroll
    for (int i = 0; i < 4; ++i) {
      int c = tid + i * 256; int row = c >> 3, sl = c & 7;
      const short* src = (row < 64)
          ? (VmT + ((size_t)bh * DK + row) * LSEQ)
          : (VsT + ((size_t)bh * DK + (row - 64)) * LSEQ);
      *(int4*)&Vt_t[row][sl * 8] = *(const int4*)(src + k0 + sl * 8);
    }
    __syncthreads();

    // S = Qm.Km^T + Qs.Ks^T for this wave's 16 q-rows x 64 k-cols
#pragma unroll
    for (int jt = 0; jt < 4; ++jt) {
      bf16x8 bm0 = *(const bf16x8*)&Km_t[jt * 16 + lr][lg * 8];
      bf16x8 bm1 = *(const bf16x8*)&Km_t[jt * 16 + lr][32 + lg * 8];
      bf16x8 bs0 = *(const bf16x8*)&Ks_t[jt * 16 + lr][lg * 8];
      bf16x8 bs1 = *(const bf16x8*)&Ks_t[jt * 16 + lr][32 + lg * 8];
      f32x4 s = {0.f, 0.f, 0.f, 0.f};
      s = MFMA16(qm[0], bm0, s);
      s = MFMA16(qm[1], bm1, s);
      s = MFMA16(qs[0], bs0, s);
      s = MFMA16(qs[1], bs1, s);
      float sk = sqk[(size_t)bh * LSEQ + k0 + jt * 16 + lr];
#pragma unroll
      for (int r = 0; r < 4; ++r) {
        float w2 = sq_row[r] + sk - 2.f * s[r];
        float wd = sqrtf(fmaxf(w2, 0.f));
        float sim = __expf(-wd);
        float p = __expf(sim);     // softmax numerator: exp(similarity)
        prs[r] += p;
        P_t[w][4 * lg + r][jt * 16 + lr] = f2bs(p);
      }
    }
    // PV: acc[16 q x 128 vcols] += P @ [Vm | Vs]   (per-wave P region, no barrier)
#pragma unroll
    for (int kh = 0; kh < 2; ++kh) {
      bf16x8 pa = *(const bf16x8*)&P_t[w][lr][kh * 32 + lg * 8];
#pragma unroll
      for (int vt = 0; vt < 8; ++vt) {
        bf16x8 vb = *(const bf16x8*)&Vt_t[vt * 16 + lr][kh * 32 + lg * 8];
        acc[vt] = MFMA16(pa, vb, acc[vt]);
      }
    }
  }

  // reduce row sums over the 16 lanes of each row-group
#pragma unroll
  for (int r = 0; r < 4; ++r) {
    float v = prs[r];
    v += __shfl_xor(v, 1); v += __shfl_xor(v, 2);
    v += __shfl_xor(v, 4); v += __shfl_xor(v, 8);
    prs[r] = v;
  }
  float inv[4];
#pragma unroll
  for (int r = 0; r < 4; ++r) inv[r] = 1.f / prs[r];

  int b = bh >> 4, h = bh & 15;
#pragma unroll
  for (int vt = 0; vt < 8; ++vt) {
    short* obuf = (vt < 4) ? Om : Os;
    int vd = (vt & 3) * 16 + lr;
#pragma unroll
    for (int r = 0; r < 4; ++r) {
      int tok = q0 + w * 16 + 4 * lg + r;
      obuf[((size_t)(b * LSEQ + tok)) * DMODEL + h * DK + vd] = f2bs(acc[vt][r] * inv[r]);
    }
  }
}

extern "C" void kernel_launch(void* const* d_in, const int* in_sizes, int n_in,
                              void* d_out, int out_size, void* d_ws, size_t ws_size,
                              hipStream_t stream) {
  const float* mu    = (const float*)d_in[0];
  const float* sigma = (const float*)d_in[1];
  const float* Wqm   = (const float*)d_in[2];
  const float* bqm   = (const float*)d_in[3];
  const float* Wqs   = (const float*)d_in[4];
  const float* bqs   = (const float*)d_in[5];
  const float* Wo    = (const float*)d_in[6];
  const float* bo    = (const float*)d_in[7];
  float* out = (float*)d_out;
  char* ws = (char*)d_ws;
  const size_t MB = 1u << 20;

  short* Amu   = (short*)(ws + 0);        // 8MB, reused as Om
  short* Asg   = (short*)(ws + 8 * MB);   // 8MB, reused as Os
  short* Wqm_t = (short*)(ws + 16 * MB);  // 6MB
  short* Wqs_t = (short*)(ws + 22 * MB);  // 6MB
  short* Wo_t  = (short*)(ws + 28 * MB);  // 2MB
  short* Qm    = (short*)(ws + 30 * MB);  // 8MB each below
  short* Km    = (short*)(ws + 38 * MB);
  short* VmT   = (short*)(ws + 46 * MB);
  short* Qs    = (short*)(ws + 54 * MB);
  short* Ks    = (short*)(ws + 62 * MB);
  short* VsT   = (short*)(ws + 70 * MB);
  float* sqq   = (float*)(ws + 78 * MB);            // 256KB
  float* sqk   = (float*)(ws + 78 * MB + 256 * 1024);
  short* Om = Amu;
  short* Os = Asg;

  cvt_bf16_k<<<2048, 256, 0, stream>>>(mu, Amu, MTOT * DMODEL / 8);
  cvt_bf16_k<<<2048, 256, 0, stream>>>(sigma, Asg, MTOT * DMODEL / 8);
  cvt_tr_k<<<dim3(96, 32), 256, 0, stream>>>(Wqm, Wqm_t, 1024, 3072);
  cvt_tr_k<<<dim3(96, 32), 256, 0, stream>>>(Wqs, Wqs_t, 1024, 3072);
  cvt_tr_k<<<dim3(32, 32), 256, 0, stream>>>(Wo, Wo_t, 1024, 1024);

  gemm128_k<<<dim3(32, 24), 256, 0, stream>>>(Amu, Wqm_t, bqm, 0, nullptr, Qm, Km, VmT);
  gemm128_k<<<dim3(32, 24), 256, 0, stream>>>(Asg, Wqs_t, bqs, 0, nullptr, Qs, Ks, VsT);

  norms_k<<<512, 256, 0, stream>>>(Qm, Qs, Km, Ks, sqq, sqk);

  attn_k<<<dim3(LSEQ / 64, BH), 256, 0, stream>>>(Qm, Km, VmT, Qs, Ks, VsT, sqq, sqk, Om, Os);

  gemm128_k<<<dim3(32, 8), 256, 0, stream>>>(Om, Wo_t, bo, 1, out, nullptr, nullptr, nullptr);
  gemm128_k<<<dim3(32, 8), 256, 0, stream>>>(Os, Wo_t, bo, 1, out + (size_t)MTOT * DMODEL,
                                             nullptr, nullptr, nullptr);
}

// Round 2
// 289.832 us; speedup vs baseline: 1.8268x; 1.8268x over previous
//
#include <hip/hip_runtime.h>
#include <hip/hip_bf16.h>

#define LSEQ   2048
#define DK     64
#define NH     16
#define BS     2
#define DMODEL 1024
#define BH     (BS*NH)    // 32
#define MTOT   (BS*LSEQ)  // 4096

typedef __attribute__((ext_vector_type(8))) short bf16x8;
typedef __attribute__((ext_vector_type(4))) float f32x4;

#define MFMA16(a,b,c) __builtin_amdgcn_mfma_f32_16x16x32_bf16((a),(b),(c),0,0,0)
#define GLD_LDS(g,l) __builtin_amdgcn_global_load_lds((const __attribute__((address_space(1))) void*)(g), (__attribute__((address_space(3))) void*)(l), 16, 0, 0)

__device__ __forceinline__ short f2bs(float f) {
  union { __hip_bfloat16 h; short s; } u; u.h = __float2bfloat16(f); return u.s;
}
__device__ __forceinline__ float b2f(unsigned short s) {
  union { unsigned u; float f; } v; v.u = ((unsigned)s) << 16; return v.f;
}
// cheap round-half-up bf16 (inputs guaranteed finite, positive-safe for our use)
__device__ __forceinline__ unsigned short f2bs_c(float f) {
  union { float f; unsigned u; } v; v.f = f;
  return (unsigned short)((v.u + 0x8000u) >> 16);
}
__device__ __forceinline__ unsigned pk2c(float lo, float hi) {
  union { float f; unsigned u; } a, b; a.f = lo; b.f = hi;
  return ((a.u + 0x8000u) >> 16) | ((b.u + 0x8000u) & 0xffff0000u);
}
__device__ __forceinline__ unsigned pk2(float lo, float hi) {
  return (unsigned)(unsigned short)f2bs(lo) | (((unsigned)(unsigned short)f2bs(hi)) << 16);
}

// ---------------- f32 -> bf16 flat convert (vectorized) ----------------
__global__ __launch_bounds__(256) void cvt_bf16_k(const float* __restrict__ in,
                                                  short* __restrict__ out, int n8) {
  for (int i = blockIdx.x * blockDim.x + threadIdx.x; i < n8; i += gridDim.x * blockDim.x) {
    const float4* p = (const float4*)in + (size_t)i * 2;
    float4 a = p[0], b = p[1];
    uint4 o;
    o.x = pk2(a.x, a.y); o.y = pk2(a.z, a.w);
    o.z = pk2(b.x, b.y); o.w = pk2(b.z, b.w);
    ((uint4*)out)[i] = o;
  }
}

// ---------------- f32 [K][N] -> bf16 transposed [N][K] ----------------
__global__ __launch_bounds__(256) void cvt_tr_k(const float* __restrict__ W,
                                                short* __restrict__ Wt,
                                                int Krows, int Ncols) {
  __shared__ float tile[32][33];
  int n0 = blockIdx.x * 32, k0 = blockIdx.y * 32;
  int t = threadIdx.x;
#pragma unroll
  for (int i = 0; i < 4; ++i) {
    int idx = t + i * 256; int r = idx >> 5, c = idx & 31;
    tile[r][c] = W[(size_t)(k0 + r) * Ncols + n0 + c];
  }
  __syncthreads();
#pragma unroll
  for (int i = 0; i < 4; ++i) {
    int idx = t + i * 256; int r = idx >> 5, c = idx & 31;
    Wt[(size_t)(n0 + r) * Krows + k0 + c] = f2bs(tile[c][r]);
  }
}

// ---------------- 128x128-tile bf16 GEMM, K=1024 ----------------
// C[m][n] = sum_k A[m][k] * Bt[n][k] + bias[n]
// mode 0: QKV scatter epilogue (bf16 to Qb/Kb head-major, VTb transposed)
// mode 1: f32 row-major to outF (ld 1024)
__global__ __launch_bounds__(256) void gemm128_k(
    const short* __restrict__ A, const short* __restrict__ Bt,
    const float* __restrict__ bias, int mode,
    float* __restrict__ outF,
    short* __restrict__ Qb, short* __restrict__ Kb, short* __restrict__ VTb) {
  __shared__ short As[128 * 64];
  __shared__ short Bs[128 * 64];
  int tid = threadIdx.x, w = tid >> 6, ln = tid & 63, lg = ln >> 4, lr = ln & 15;
  int m0 = blockIdx.x * 128, n0 = blockIdx.y * 128;
  int wr = w >> 1, wc = w & 1;
  f32x4 acc[4][4] = {};

  for (int k0 = 0; k0 < 1024; k0 += 64) {
    __syncthreads();
#pragma unroll
    for (int i = 0; i < 4; ++i) {
      int cb = w * 64 + i * 256;
      int c = cb + ln;
      GLD_LDS(A  + (size_t)(m0 + (c >> 3)) * 1024 + k0 + (c & 7) * 8, &As[cb * 8]);
      GLD_LDS(Bt + (size_t)(n0 + (c >> 3)) * 1024 + k0 + (c & 7) * 8, &Bs[cb * 8]);
    }
    __syncthreads();
#pragma unroll
    for (int kh = 0; kh < 2; ++kh) {
      bf16x8 af[4], bfr[4];
#pragma unroll
      for (int mi = 0; mi < 4; ++mi)
        af[mi] = *(const bf16x8*)&As[(wr * 64 + mi * 16 + lr) * 64 + kh * 32 + lg * 8];
#pragma unroll
      for (int ni = 0; ni < 4; ++ni)
        bfr[ni] = *(const bf16x8*)&Bs[(wc * 64 + ni * 16 + lr) * 64 + kh * 32 + lg * 8];
#pragma unroll
      for (int mi = 0; mi < 4; ++mi)
#pragma unroll
        for (int ni = 0; ni < 4; ++ni)
          acc[mi][ni] = MFMA16(af[mi], bfr[ni], acc[mi][ni]);
    }
  }

#pragma unroll
  for (int ni = 0; ni < 4; ++ni) {
    int n = n0 + wc * 64 + ni * 16 + lr;
    float bv = bias[n];
    int part = n >> 10, cc = n & 1023, h = cc >> 6, dd = cc & 63;
#pragma unroll
    for (int mi = 0; mi < 4; ++mi) {
      int mbase = m0 + wr * 64 + mi * 16 + 4 * lg;
      float vv[4];
#pragma unroll
      for (int r = 0; r < 4; ++r) vv[r] = acc[mi][ni][r] + bv;
      if (mode == 1) {
#pragma unroll
        for (int r = 0; r < 4; ++r) outF[(size_t)(mbase + r) * 1024 + n] = vv[r];
      } else if (part == 2) {
        // V^T scatter: 4 consecutive tokens for fixed dim -> packed b64
        int b = mbase >> 11, tok = mbase & 2047, bh = b * NH + h;
        uint2 pk; pk.x = pk2c(vv[0], vv[1]); pk.y = pk2c(vv[2], vv[3]);
        *(uint2*)&VTb[((size_t)bh * DK + dd) * LSEQ + tok] = pk;
      } else {
        short* dst = (part == 0) ? Qb : Kb;
#pragma unroll
        for (int r = 0; r < 4; ++r) {
          int m = mbase + r;
          int b = m >> 11, tok = m & 2047, bh = b * NH + h;
          dst[((size_t)bh * LSEQ + tok) * DK + dd] = (short)f2bs_c(vv[r]);
        }
      }
    }
  }
}

// ---------------- per-row squared norms ----------------
__global__ __launch_bounds__(256) void norms_k(
    const short* __restrict__ Qm, const short* __restrict__ Qs,
    const short* __restrict__ Km, const short* __restrict__ Ks,
    float* __restrict__ sqq, float* __restrict__ sqk) {
  int id = blockIdx.x * 256 + threadIdx.x;  // 0..131071
  int row = id & 65535;
  const short* p1 = (id < 65536) ? Qm : Km;
  const short* p2 = (id < 65536) ? Qs : Ks;
  float* outp = (id < 65536) ? sqq : sqk;
  const uint4* a = (const uint4*)(p1 + (size_t)row * DK);
  const uint4* b = (const uint4*)(p2 + (size_t)row * DK);
  float s = 0.f;
#pragma unroll
  for (int i = 0; i < 8; ++i) {
    uint4 x = a[i], y = b[i];
    unsigned vx[4] = {x.x, x.y, x.z, x.w};
    unsigned vy[4] = {y.x, y.y, y.z, y.w};
#pragma unroll
    for (int j = 0; j < 4; ++j) {
      float l1 = b2f((unsigned short)(vx[j] & 0xffff)), h1 = b2f((unsigned short)(vx[j] >> 16));
      float l2 = b2f((unsigned short)(vy[j] & 0xffff)), h2 = b2f((unsigned short)(vy[j] >> 16));
      s += l1 * l1 + h1 * h1 + l2 * l2 + h2 * h2;
    }
  }
  outp[row] = s;
}

// ---------------- fused Wasserstein attention ----------------
// grid (L/128, BH); 512 threads = 8 waves, wave w owns q-rows [q0+16w, q0+16w+16)
// Register-double-buffered K/V staging (T14): prefetch next tile into regs
// during compute, write to LDS after the barrier.
__global__ __launch_bounds__(512, 4) void attn_k(
    const short* __restrict__ Qm, const short* __restrict__ Km, const short* __restrict__ VmT,
    const short* __restrict__ Qs, const short* __restrict__ Ks, const short* __restrict__ VsT,
    const float* __restrict__ sqq, const float* __restrict__ sqk,
    short* __restrict__ Om, short* __restrict__ Os) {
  int bh = blockIdx.y;
  int q0 = blockIdx.x * 128;
  int tid = threadIdx.x, w = tid >> 6, ln = tid & 63, lg = ln >> 4, lr = ln & 15;

  __shared__ short Km_t[64][72];
  __shared__ short Ks_t[64][72];
  __shared__ short Vt_t[128][72];
  __shared__ short P_t[8][16][72];

  const size_t bhQ = (size_t)bh * LSEQ * DK;

  // Q fragments for this wave's 16 rows (A-frag: row=lr, k = lg*8 + kh*32)
  bf16x8 qm[2], qs[2];
  {
    const short* qpm = Qm + bhQ + (size_t)(q0 + w * 16 + lr) * DK;
    const short* qps = Qs + bhQ + (size_t)(q0 + w * 16 + lr) * DK;
    qm[0] = *(const bf16x8*)(qpm + lg * 8);
    qm[1] = *(const bf16x8*)(qpm + 32 + lg * 8);
    qs[0] = *(const bf16x8*)(qps + lg * 8);
    qs[1] = *(const bf16x8*)(qps + 32 + lg * 8);
  }
  float sq_row[4];
#pragma unroll
  for (int r = 0; r < 4; ++r)
    sq_row[r] = sqq[(size_t)bh * LSEQ + q0 + w * 16 + 4 * lg + r];

  // staging geometry: 512 threads
  // K tiles: 64 rows x 64 shorts = 512 int4 slots -> 1 each
  int kr = tid >> 3, ksl = tid & 7;
  // V tile: 128 rows x 64 shorts = 1024 int4 slots -> 2 each (rows tid>>3 and +64)
  const short* kmsrc = Km + bhQ + (size_t)kr * DK + ksl * 8;
  const short* kssrc = Ks + bhQ + (size_t)kr * DK + ksl * 8;
  const short* vsrc0 = VmT + ((size_t)bh * DK + kr) * LSEQ + ksl * 8;
  const short* vsrc1 = VsT + ((size_t)bh * DK + kr) * LSEQ + ksl * 8;

  int4 rKm, rKs, rV0, rV1;
  {
    rKm = *(const int4*)(kmsrc);
    rKs = *(const int4*)(kssrc);
    rV0 = *(const int4*)(vsrc0);
    rV1 = *(const int4*)(vsrc1);
  }

  f32x4 acc[8] = {};
  float prs[4] = {0.f, 0.f, 0.f, 0.f};

  for (int kt = 0; kt < LSEQ / 64; ++kt) {
    int k0 = kt * 64;
    __syncthreads();   // all reads of previous tile done
    *(int4*)&Km_t[kr][ksl * 8] = rKm;
    *(int4*)&Ks_t[kr][ksl * 8] = rKs;
    *(int4*)&Vt_t[kr][ksl * 8] = rV0;
    *(int4*)&Vt_t[kr + 64][ksl * 8] = rV1;
    __syncthreads();   // staged tile visible

    // prefetch next tile into registers (clamped; latency hides under compute)
    {
      int k0n = (kt < LSEQ / 64 - 1) ? (k0 + 64) : k0;
      rKm = *(const int4*)(kmsrc + (size_t)k0n * DK);
      rKs = *(const int4*)(kssrc + (size_t)k0n * DK);
      rV0 = *(const int4*)(vsrc0 + k0n);
      rV1 = *(const int4*)(vsrc1 + k0n);
    }

    // S = Qm.Km^T + Qs.Ks^T for this wave's 16 q-rows x 64 k-cols
#pragma unroll
    for (int jt = 0; jt < 4; ++jt) {
      bf16x8 bm0 = *(const bf16x8*)&Km_t[jt * 16 + lr][lg * 8];
      bf16x8 bm1 = *(const bf16x8*)&Km_t[jt * 16 + lr][32 + lg * 8];
      bf16x8 bs0 = *(const bf16x8*)&Ks_t[jt * 16 + lr][lg * 8];
      bf16x8 bs1 = *(const bf16x8*)&Ks_t[jt * 16 + lr][32 + lg * 8];
      f32x4 s = {0.f, 0.f, 0.f, 0.f};
      s = MFMA16(qm[0], bm0, s);
      s = MFMA16(qm[1], bm1, s);
      s = MFMA16(qs[0], bs0, s);
      s = MFMA16(qs[1], bs1, s);
      float skv = sqk[(size_t)bh * LSEQ + k0 + jt * 16 + lr];
#pragma unroll
      for (int r = 0; r < 4; ++r) {
        float w2 = fmaf(-2.f, s[r], sq_row[r] + skv);
        float wd = __builtin_amdgcn_sqrtf(fmaxf(w2, 0.f));
        float sim = __expf(-wd);
        float p = __expf(sim);     // softmax numerator: exp(similarity)
        prs[r] += p;
        P_t[w][4 * lg + r][jt * 16 + lr] = (short)f2bs_c(p);
      }
    }
    // PV (swapped operands): acc[vt] = D[v][q], A=V^T frag, B=P frag
#pragma unroll
    for (int kh = 0; kh < 2; ++kh) {
      bf16x8 pa = *(const bf16x8*)&P_t[w][lr][kh * 32 + lg * 8];
#pragma unroll
      for (int vt = 0; vt < 8; ++vt) {
        bf16x8 vb = *(const bf16x8*)&Vt_t[vt * 16 + lr][kh * 32 + lg * 8];
        acc[vt] = MFMA16(vb, pa, acc[vt]);
      }
    }
  }

  // row sums: prs[r] is partial sum for q=4lg+r over this lane's 16 k-cols.
  // reduce over the 16 lanes of each group.
#pragma unroll
  for (int r = 0; r < 4; ++r) {
    float v = prs[r];
    v += __shfl_xor(v, 1); v += __shfl_xor(v, 2);
    v += __shfl_xor(v, 4); v += __shfl_xor(v, 8);
    prs[r] = v;
  }
  // lane needs sum for q = lr: source group lg' = lr>>2, index r' = lr&3
  float vv = prs[0];
  if ((lr & 3) == 1) vv = prs[1];
  if ((lr & 3) == 2) vv = prs[2];
  if ((lr & 3) == 3) vv = prs[3];
  float sumq = __shfl(vv, ((lr >> 2) << 4) + lr);
  float inv = 1.f / sumq;

  int b = bh >> 4, h = bh & 15;
  int tok = q0 + w * 16 + lr;
  size_t orow = ((size_t)(b * LSEQ + tok)) * DMODEL + h * DK;
#pragma unroll
  for (int vt = 0; vt < 8; ++vt) {
    short* obuf = (vt < 4) ? Om : Os;
    int vd = (vt & 3) * 16 + 4 * lg;
    float a0 = acc[vt][0] * inv, a1 = acc[vt][1] * inv;
    float a2 = acc[vt][2] * inv, a3 = acc[vt][3] * inv;
    uint2 pk; pk.x = pk2c(a0, a1); pk.y = pk2c(a2, a3);
    *(uint2*)(obuf + orow + vd) = pk;
  }
}

extern "C" void kernel_launch(void* const* d_in, const int* in_sizes, int n_in,
                              void* d_out, int out_size, void* d_ws, size_t ws_size,
                              hipStream_t stream) {
  const float* mu    = (const float*)d_in[0];
  const float* sigma = (const float*)d_in[1];
  const float* Wqm   = (const float*)d_in[2];
  const float* bqm   = (const float*)d_in[3];
  const float* Wqs   = (const float*)d_in[4];
  const float* bqs   = (const float*)d_in[5];
  const float* Wo    = (const float*)d_in[6];
  const float* bo    = (const float*)d_in[7];
  float* out = (float*)d_out;
  char* ws = (char*)d_ws;
  const size_t MB = 1u << 20;

  short* Amu   = (short*)(ws + 0);        // 8MB, reused as Om
  short* Asg   = (short*)(ws + 8 * MB);   // 8MB, reused as Os (contiguous with Om!)
  short* Wqm_t = (short*)(ws + 16 * MB);  // 6MB
  short* Wqs_t = (short*)(ws + 22 * MB);  // 6MB
  short* Wo_t  = (short*)(ws + 28 * MB);  // 2MB
  short* Qm    = (short*)(ws + 30 * MB);  // 8MB each below
  short* Km    = (short*)(ws + 38 * MB);
  short* VmT   = (short*)(ws + 46 * MB);
  short* Qs    = (short*)(ws + 54 * MB);
  short* Ks    = (short*)(ws + 62 * MB);
  short* VsT   = (short*)(ws + 70 * MB);
  float* sqq   = (float*)(ws + 78 * MB);            // 256KB
  float* sqk   = (float*)(ws + 78 * MB + 256 * 1024);
  short* Om = Amu;
  short* Os = Asg;

  cvt_bf16_k<<<2048, 256, 0, stream>>>(mu, Amu, MTOT * DMODEL / 8);
  cvt_bf16_k<<<2048, 256, 0, stream>>>(sigma, Asg, MTOT * DMODEL / 8);
  cvt_tr_k<<<dim3(96, 32), 256, 0, stream>>>(Wqm, Wqm_t, 1024, 3072);
  cvt_tr_k<<<dim3(96, 32), 256, 0, stream>>>(Wqs, Wqs_t, 1024, 3072);
  cvt_tr_k<<<dim3(32, 32), 256, 0, stream>>>(Wo, Wo_t, 1024, 1024);

  gemm128_k<<<dim3(32, 24), 256, 0, stream>>>(Amu, Wqm_t, bqm, 0, nullptr, Qm, Km, VmT);
  gemm128_k<<<dim3(32, 24), 256, 0, stream>>>(Asg, Wqs_t, bqs, 0, nullptr, Qs, Ks, VsT);

  norms_k<<<512, 256, 0, stream>>>(Qm, Qs, Km, Ks, sqq, sqk);

  attn_k<<<dim3(LSEQ / 128, BH), 512, 0, stream>>>(Qm, Km, VmT, Qs, Ks, VsT, sqq, sqk, Om, Os);

  // out-proj for mu and sigma as ONE GEMM: Om|Os are contiguous (M=8192),
  // and out_mu|out_sigma are contiguous in d_out.
  gemm128_k<<<dim3(64, 8), 256, 0, stream>>>(Om, Wo_t, bo, 1, out, nullptr, nullptr, nullptr);
}